// Round 17
// baseline (260.287 us; speedup 1.0000x reference)
//
#include <hip/hip_runtime.h>
#include <hip/hip_bf16.h>

#define NB   32
#define SEQ  512
#define HID  768
#define FFN  3072
#define NEXP 8

typedef float f32x4 __attribute__((ext_vector_type(4)));
typedef short s16x8 __attribute__((ext_vector_type(8)));

__device__ __forceinline__ unsigned short f2bf(float f) {
    return __builtin_bit_cast(unsigned short, (__bf16)f);
}

__device__ __forceinline__ float fast_exp2(float x) {
    float r; asm("v_exp_f32 %0, %1" : "=v"(r) : "v"(x)); return r;
}
__device__ __forceinline__ float fast_rcp(float x) {
    float r; asm("v_rcp_f32 %0, %1" : "=v"(r) : "v"(x)); return r;
}

// tanh-gelu, overflow-free (exp2 arg <= 0). |error| vs exact-erf gelu ~2e-4.
__device__ __forceinline__ float gelu_fast(float v) {
    float u  = v * (0.7978845608f + 0.0356774081f * v * v);
    float t  = fast_exp2(-2.8853900817779268f * fabsf(u));
    float T  = (1.0f - t) * fast_rcp(1.0f + t);
    return 0.5f * v + 0.5f * fabsf(v) * T;
}

#define GLOAD16(gp, lp) __builtin_amdgcn_global_load_lds( \
    (const __attribute__((address_space(1))) unsigned int*)(gp), \
    (__attribute__((address_space(3))) unsigned int*)(lp), 16, 0, 0)

#define VMCNT(N) asm volatile("s_waitcnt vmcnt(%0)" :: "i"(N) : "memory")

// physical XCD id (m09: returns 0..7 on MI355X)
__device__ __forceinline__ int get_xcc() {
    int x;
    asm volatile("s_getreg_b32 %0, hwreg(HW_REG_XCC_ID)" : "=s"(x));
    return x & 7;
}

__device__ __forceinline__ int claim_item(int* cnt, int myx, int Q) {
#pragma unroll 1
    for (int t = 0; t < 8; ++t) {
        int x = (myx + t) & 7;
        int s = atomicAdd(&cnt[x], 1);
        if (s < Q) return x * Q + s;
    }
    return -1;
}

// ===========================================================================
// Packed tile layout (per 256x64-elem K-tile, 32768 B):
//   [half(2)][rr(128)][q(128 B)] with pre-applied XOR swizzle.
//   A-map: row = (rr&63) + ((rr>>6)<<7) + half*64
//   B-map: row = (rr&31) + ((rr>>5)<<6) + half*32
// ===========================================================================

__device__ __forceinline__ void cvt_w_body(
    const float* __restrict__ W, unsigned short* __restrict__ WP,
    unsigned short (*tile)[65], int nx, int ny, int bx, int by, int bz)
{
    const int C = nx * 64, R = ny * 64;
    const int cbg = bx * 64, rbg = by * 64;
    const float* src = W + (size_t)bz * R * C;
    const int x = threadIdx.x & 63, y0 = threadIdx.x >> 6;
#pragma unroll
    for (int i = 0; i < 16; i++) {
        int r = y0 + i * 4;
        tile[r][x] = f2bf(src[(size_t)(rbg + r) * C + cbg + x]);
    }
    __syncthreads();

    const int nt  = bx >> 2;
    const int NTn = nx >> 2;
    const int kt  = by;
    const int KT  = ny;
    char* out = (char*)WP + ((size_t)(bz * NTn + nt) * KT + kt) * 32768;

#pragma unroll
    for (int i = 0; i < 2; i++) {
        int cc  = threadIdx.x + i * 256;
        int n64 = cc >> 3, kc = cc & 7;
        int row = (bx & 3) * 64 + n64;
        int half = (row >> 5) & 1;
        int rr   = (row & 31) | (((row >> 6) & 3) << 5);
        int q    = (kc * 16) ^ ((row & 7) << 4);
        unsigned short o[8];
#pragma unroll
        for (int j = 0; j < 8; j++) o[j] = tile[kc * 8 + j][n64];
        *(s16x8*)(out + half * 16384 + rr * 128 + q) = *(s16x8*)o;
    }
}

__global__ __launch_bounds__(256) void prep_all(
    const float* __restrict__ X, const float* __restrict__ W1,
    const float* __restrict__ W2, const int* __restrict__ labels,
    unsigned short* __restrict__ XbP, unsigned short* __restrict__ W1P,
    unsigned short* __restrict__ W2P, int* __restrict__ perm)
{
    __shared__ unsigned short tile[64][65];
    const int bid = blockIdx.x;
    if (bid == 0) {
        int i = threadIdx.x;
        if (i < NB) {
            int li = labels[i];
            int rank = 0;
            for (int j = 0; j < NB; j++) {
                int lj = labels[j];
                if (lj < li || (lj == li && j < i)) rank++;
            }
            perm[rank] = i;
        }
        return;
    }
    if (bid <= 768) {
        const int b  = bid - 1;
        const int kt = b % 12;
        const int mt = (b / 12) & 1;
        const int bs = b / 24;
        const float* src = X + ((size_t)bs * SEQ + (size_t)mt * 256) * HID + kt * 64;
        char* out = (char*)XbP + (size_t)b * 32768;
#pragma unroll
        for (int i = 0; i < 8; i++) {
            int c = threadIdx.x + i * 256;
            int half = c >> 10;
            int rr   = (c >> 3) & 127;
            int c16  = c & 7;
            int row  = (rr & 63) + ((rr >> 6) << 7) + half * 64;
            int tb   = (c16 * 16) ^ ((row & 7) << 4);
            const float* sp = src + (size_t)row * HID + (tb >> 1);
            f32x4 a = *(const f32x4*)sp;
            f32x4 b4 = *(const f32x4*)(sp + 4);
            unsigned short o[8];
#pragma unroll
            for (int v = 0; v < 4; v++) o[v] = f2bf(a[v]);
#pragma unroll
            for (int v = 0; v < 4; v++) o[4 + v] = f2bf(b4[v]);
            *(s16x8*)(out + (size_t)c * 16) = *(s16x8*)o;
        }
        return;
    }
    if (bid <= 768 + 4608) {
        int idx = bid - 769;
        cvt_w_body(W1, W1P, tile, 48, 12, idx % 48, (idx / 48) % 12, idx / 576);
        return;
    }
    {
        int idx = bid - (769 + 4608);
        cvt_w_body(W2, W2P, tile, 12, 48, idx % 12, (idx / 12) % 48, idx / 576);
    }
}

// ---------------------------------------------------------------------------
// Linear staging of one 16-KB region from a packed tile.
// ---------------------------------------------------------------------------
template<bool ISA>
__device__ __forceinline__ void stage_lin(const char* tile, char* lds, int half, int tid)
{
#pragma unroll
    for (int p = 0; p < 2; p++) {
        int L  = p * 8192 + tid * 16;
        int rr = L >> 7;
        int cb = L & 127;
        int row = ISA ? ((rr & 63) + ((rr >> 6) << 7) + half * 64)
                      : ((rr & 31) + ((rr >> 5) << 6) + half * 32);
        GLOAD16(tile + half * 16384 + L, lds + (size_t)row * 128 + cb);
    }
}

__device__ __forceinline__ void read_af(const char* Ab, int arow_b, int k0, int ih, s16x8 (&a)[2][4])
{
    const int k1 = k0 ^ 64;
#pragma unroll
    for (int i = 0; i < 4; i++) {
        const char* p = Ab + arow_b + (ih * 64 + i * 16) * 128;
        a[0][i] = *(const s16x8*)(p + k0);
        a[1][i] = *(const s16x8*)(p + k1);
    }
}
__device__ __forceinline__ void read_bf(const char* Bb, int brow_b, int k0, int jh, s16x8 (&b)[2][2])
{
    const int k1 = k0 ^ 64;
#pragma unroll
    for (int j = 0; j < 2; j++) {
        const char* p = Bb + brow_b + (jh * 32 + j * 16) * 128;
        b[0][j] = *(const s16x8*)(p + k0);
        b[1][j] = *(const s16x8*)(p + k1);
    }
}

template<int IH, int JH>
__device__ __forceinline__ void mfma_quad(s16x8 (&a)[2][4], s16x8 (&b)[2][2], f32x4 (&acc)[8][4])
{
    __builtin_amdgcn_s_setprio(1);
#pragma unroll
    for (int kk = 0; kk < 2; kk++)
#pragma unroll
        for (int i = 0; i < 4; i++)
#pragma unroll
            for (int j = 0; j < 2; j++)
                acc[IH * 4 + i][JH * 2 + j] = __builtin_amdgcn_mfma_f32_16x16x32_bf16(
                    a[kk][i], b[kk][j], acc[IH * 4 + i][JH * 2 + j], 0, 0, 0);
    __builtin_amdgcn_s_setprio(0);
}

// ======================= gemm1: B-direct-to-register =======================
__device__ __forceinline__ void load_b8(const char* bt, const int* boff, s16x8 (&b)[8])
{
#pragma unroll
    for (int i = 0; i < 8; i++)
        b[i] = *(const s16x8*)(bt + boff[i]);
}

// b index = jh*4 + j*2 + kk
template<int IH>
__device__ __forceinline__ void mfma_half(s16x8 (&a)[2][4], s16x8 (&b)[8], f32x4 (&acc)[8][4])
{
    __builtin_amdgcn_s_setprio(1);
#pragma unroll
    for (int kk = 0; kk < 2; kk++)
#pragma unroll
        for (int i = 0; i < 4; i++)
#pragma unroll
            for (int jh = 0; jh < 2; jh++)
#pragma unroll
                for (int j = 0; j < 2; j++)
                    acc[IH * 4 + i][jh * 2 + j] = __builtin_amdgcn_mfma_f32_16x16x32_bf16(
                        a[kk][i], b[jh * 4 + j * 2 + kk], acc[IH * 4 + i][jh * 2 + j], 0, 0, 0);
    __builtin_amdgcn_s_setprio(0);
}

// one window, 2 barriers. bC = B(w) frags (consumed here); AFTER last use it
// is reloaded in-place with B(w+2) (proper reload-after-last-use dbuf —
// fixes R16's aliasing bug which clobbered the OTHER buffer's live B(w+1)).
template<bool STG, int VM>
__device__ __forceinline__ void bwin(const char* At2, const char* Bt2,
    char* bufc, const int* boff, int arow_b, int k0, int tid,
    s16x8 (&bC)[8], f32x4 (&acc)[8][4])
{
    s16x8 a[2][4];
    read_af(bufc, arow_b, k0, 0, a);
    mfma_half<0>(a, bC, acc);
    read_af(bufc, arow_b, k0, 1, a);
    asm volatile("s_waitcnt lgkmcnt(0)" ::: "memory");
    __builtin_amdgcn_s_barrier();
    if constexpr (STG) {
        stage_lin<true>(At2, bufc, 0, tid);   // A(w+2) -> this buffer
        stage_lin<true>(At2, bufc, 1, tid);
    }
    mfma_half<1>(a, bC, acc);                 // last use of bC = B(w)
    if constexpr (STG) load_b8(Bt2, boff, bC); // reload SAME regs with B(w+2)
    if constexpr (VM >= 0) VMCNT(VM);
    __builtin_amdgcn_s_barrier();
}

// ---------------------------------------------------------------------------
// Kernel 1: G = gelu(XbP @ W1P[e] + b1[e]) -> packed-A GP tiles.
// A: gload_lds dbuf (2 x 32 KB). B: direct global->reg, reload-in-place dbuf.
// 2 barriers/window, counted VMCNT(20) (A(w+1) guard), never 0 mid-loop.
// ---------------------------------------------------------------------------
__global__ __launch_bounds__(512, 2) void moe_gemm1(
    const unsigned short* __restrict__ XbP,
    const int*   __restrict__ labels,
    const int*   __restrict__ perm,
    const unsigned short* __restrict__ W1P,
    const float* __restrict__ B1,
    unsigned short* __restrict__ GP,
    int* __restrict__ cnt1)
{
    extern __shared__ char smem[];
    const int tid = threadIdx.x;
    const int myx = get_xcc();
    if (tid == 0) ((volatile int*)smem)[0] = claim_item(cnt1, myx, 96);
    __syncthreads();
    const int item = ((volatile int*)smem)[0];
    __syncthreads();
    if (item < 0) return;

    const int x    = item / 96;
    const int s    = item % 96;
    const int band = s >> 5;
    const int i    = s & 31;
    const int pair = i >> 2;
    const int c    = i & 3;
    const int bs = perm[x * 4 + (pair >> 1)];
    const int mt = pair & 1;
    const int nt = band * 4 + c;
    const int e  = labels[bs];

    const char* At = (const char*)XbP + (size_t)((bs * 2 + mt) * 12) * 32768;
    const char* Bt = (const char*)W1P + (size_t)((e * 12 + nt) * 12) * 32768;

    const int lane = tid & 63, w = tid >> 6;
    const int wm = (w >> 2) * 128, wn = (w & 3) * 64;
    const int fr = lane & 15, fq = lane >> 4;
    const int arow_b = (wm + fr) * 128;
    const int k0 = (fq * 16) ^ ((fr & 7) << 4);

    // per-lane B-fragment offsets within a packed 32-KB tile
    int boff[8];
#pragma unroll
    for (int jh = 0; jh < 2; jh++)
#pragma unroll
        for (int j = 0; j < 2; j++) {
            int row  = wn + jh * 32 + j * 16 + fr;
            int base = ((row >> 5) & 1) * 16384 +
                       (((row & 31) | (((row >> 6) & 3) << 5))) * 128;
#pragma unroll
            for (int kk = 0; kk < 2; kk++)
                boff[jh * 4 + j * 2 + kk] = base + ((kk * 64 + fq * 16) ^ ((row & 7) << 4));
        }

    f32x4 acc[8][4];
#pragma unroll
    for (int i2 = 0; i2 < 8; i2++)
#pragma unroll
        for (int j = 0; j < 4; j++) acc[i2][j] = (f32x4)0.0f;

    s16x8 bE[8], bO[8];
    // prologue: A(0)->buf0, A(1)->buf1 (4+4 loads), B(0)->bE, B(1)->bO (8+8)
    stage_lin<true>(At,          smem,          0, tid);
    stage_lin<true>(At,          smem,          1, tid);
    stage_lin<true>(At + 32768,  smem + 32768,  0, tid);
    stage_lin<true>(At + 32768,  smem + 32768,  1, tid);
    load_b8(Bt,          boff, bE);
    load_b8(Bt + 32768,  boff, bO);
    VMCNT(20);                 // A(0) landed (newest 20 = A1:4 + B0:8 + B1:8)
    __builtin_amdgcn_s_barrier();

#pragma unroll 1
    for (int ww = 0; ww < 10; ww += 2) {
        // window ww: consume bE=B(ww); reload bE <- B(ww+2)
        bwin<true, 20>(At + (size_t)(ww + 2) * 32768, Bt + (size_t)(ww + 2) * 32768,
                       smem,         boff, arow_b, k0, tid, bE, acc);
        // window ww+1: consume bO=B(ww+1); reload bO <- B(ww+3)
        bwin<true, 20>(At + (size_t)(ww + 3) * 32768, Bt + (size_t)(ww + 3) * 32768,
                       smem + 32768, boff, arow_b, k0, tid, bO, acc);
    }
    bwin<false, 8>(nullptr, nullptr, smem,         boff, arow_b, k0, tid, bE, acc);
    bwin<false, -1>(nullptr, nullptr, smem + 32768, boff, arow_b, k0, tid, bO, acc);

    asm volatile("s_waitcnt lgkmcnt(0)" ::: "memory");
    __syncthreads();

    // ---- epilogue: bias+gelu -> LDS [256][512B] swizzled -> linear NT ----
    const float* b1g = B1 + (size_t)e * FFN + (size_t)nt * 256;
    float bias[4];
#pragma unroll
    for (int nj = 0; nj < 4; nj++) bias[nj] = b1g[wn + nj * 16 + fr];
#pragma unroll
    for (int mi = 0; mi < 8; mi++)
#pragma unroll
        for (int nj = 0; nj < 4; nj++) {
            const int col = wn + nj * 16 + fr;
#pragma unroll
            for (int r2 = 0; r2 < 4; r2++) {
                const int row = wm + mi * 16 + fq * 4 + r2;
                float v = acc[mi][nj][r2] + bias[nj];
                int byte = row * 512 + ((col * 2) ^ ((row & 7) << 4));
                *(unsigned short*)(smem + byte) = f2bf(gelu_fast(v));
            }
        }
    __syncthreads();
    char* GPb = (char*)GP + ((size_t)(bs * 2 + mt) * 48 + (size_t)nt * 4) * 32768;
#pragma unroll
    for (int it = 0; it < 16; it++) {
        int c2 = tid + it * 512;
        int kt2l = c2 >> 11;
        int reg  = (c2 >> 10) & 1;
        int rr2  = (c2 >> 3) & 127;
        int c16  = c2 & 7;
        int row  = (rr2 & 63) + ((rr2 >> 6) << 7) + reg * 64;
        s16x8 v = *(const s16x8*)(smem + row * 512 + kt2l * 128 + c16 * 16);
        __builtin_nontemporal_store(v,
            (s16x8*)(GPb + (size_t)kt2l * 32768 + (size_t)(c2 & 2047) * 16));
    }
}

// ======================= gemm2 (R15, unchanged) ============================
template<bool S1, bool S2, int VM>
__device__ __forceinline__ void gwindowT(
    const char* tA1, const char* tB1, const char* tA0, const char* tB0,
    char* Acur, char* Bcur, char* Anxt, char* Bnxt,
    int arow_b, int brow_b, int k0, int tid, f32x4 (&acc)[8][4])
{
    s16x8 a[2][4], b0[2][2], b1[2][2];
    read_af(Acur, arow_b, k0, 0, a);
    read_bf(Bcur, brow_b, k0, 0, b0);
    if constexpr (S1) stage_lin<true >(tA1, Anxt, 1, tid);
    __builtin_amdgcn_s_barrier();
    mfma_quad<0, 0>(a, b0, acc);
    __builtin_amdgcn_s_barrier();
    read_bf(Bcur, brow_b, k0, 1, b1);
    if constexpr (S1) stage_lin<false>(tB1, Bnxt, 1, tid);
    __builtin_amdgcn_s_barrier();
    mfma_quad<0, 1>(a, b1, acc);
    __builtin_amdgcn_s_barrier();
    read_af(Acur, arow_b, k0, 1, a);
    if constexpr (S2) stage_lin<true >(tA0, Acur, 0, tid);
    __builtin_amdgcn_s_barrier();
    mfma_quad<1, 1>(a, b1, acc);
    __builtin_amdgcn_s_barrier();
    if constexpr (S2) stage_lin<false>(tB0, Bcur, 0, tid);
    __builtin_amdgcn_s_barrier();
    mfma_quad<1, 0>(a, b0, acc);
    if constexpr (VM >= 0) VMCNT(VM);
    __builtin_amdgcn_s_barrier();
}

__device__ __forceinline__ void mainloopT(const char* At, const char* Bt, int KT,
    char* smem, int tid, int arow_b, int brow_b, int k0, f32x4 (&acc)[8][4])
{
    stage_lin<true >(At,          smem,          0, tid);
    stage_lin<false>(Bt,          smem + 65536,  0, tid);
    stage_lin<true >(At,          smem,          1, tid);
    stage_lin<false>(Bt,          smem + 65536,  1, tid);
    stage_lin<true >(At + 32768,  smem + 32768,  0, tid);
    stage_lin<false>(Bt + 32768,  smem + 98304,  0, tid);
    VMCNT(4);
    __builtin_amdgcn_s_barrier();

    int cur = 0;
    for (int kt = 0; kt < KT - 2; ++kt) {
        char* Ac = smem + (cur << 15);
        char* An = smem + ((cur ^ 1) << 15);
        char* Bc = smem + 65536 + (cur << 15);
        char* Bn = smem + 65536 + ((cur ^ 1) << 15);
        gwindowT<true, true, 4>(At + (size_t)(kt + 1) * 32768, Bt + (size_t)(kt + 1) * 32768,
                                At + (size_t)(kt + 2) * 32768, Bt + (size_t)(kt + 2) * 32768,
                                Ac, Bc, An, Bn, arow_b, brow_b, k0, tid, acc);
        cur ^= 1;
    }
    {
        char* Ac = smem + (cur << 15);
        char* An = smem + ((cur ^ 1) << 15);
        char* Bc = smem + 65536 + (cur << 15);
        char* Bn = smem + 65536 + ((cur ^ 1) << 15);
        gwindowT<true, false, 0>(At + (size_t)(KT - 1) * 32768, Bt + (size_t)(KT - 1) * 32768,
                                 nullptr, nullptr, Ac, Bc, An, Bn, arow_b, brow_b, k0, tid, acc);
        cur ^= 1;
    }
    {
        char* Ac = smem + (cur << 15);
        char* An = smem + ((cur ^ 1) << 15);
        char* Bc = smem + 65536 + (cur << 15);
        char* Bn = smem + 65536 + ((cur ^ 1) << 15);
        gwindowT<false, false, -1>(nullptr, nullptr, nullptr, nullptr,
                                   Ac, Bc, An, Bn, arow_b, brow_b, k0, tid, acc);
    }
}

__global__ __launch_bounds__(512, 2) void moe_gemm2(
    const unsigned short* __restrict__ GP,
    const int*   __restrict__ labels,
    const int*   __restrict__ perm,
    const unsigned short* __restrict__ W2P,
    const float* __restrict__ B2,
    float* __restrict__ Out,
    int* __restrict__ cnt2)
{
    extern __shared__ char smem[];
    const int tid = threadIdx.x;
    const int myx = get_xcc();
    if (tid == 0) ((volatile int*)smem)[0] = claim_item(cnt2, myx, 24);
    __syncthreads();
    const int item = ((volatile int*)smem)[0];
    __syncthreads();
    if (item < 0) return;

    const int x = item / 24;
    const int s = item % 24;
    const int bs = perm[x * 4 + s / 6];
    const int rr = s % 6;
    const int mt = rr / 3, nt = rr % 3;
    const int e  = labels[bs];

    const char* At = (const char*)GP  + (size_t)((bs * 2 + mt) * 48) * 32768;
    const char* Bt = (const char*)W2P + (size_t)((e * 3 + nt) * 48) * 32768;

    const int lane = tid & 63, w = tid >> 6;
    const int wm = (w >> 2) * 128, wn = (w & 3) * 64;
    const int fr = lane & 15, fq = lane >> 4;
    const int arow_b = (wm + fr) * 128, brow_b = (wn + fr) * 128;
    const int k0 = (fq * 16) ^ ((fr & 7) << 4);

    f32x4 acc[8][4];
#pragma unroll
    for (int i = 0; i < 8; i++)
#pragma unroll
        for (int j = 0; j < 4; j++) acc[i][j] = (f32x4)0.0f;

    mainloopT(At, Bt, 48, smem, tid, arow_b, brow_b, k0, acc);

    const float* b2g = B2 + (size_t)e * HID + (size_t)nt * 256;
    float bias[4];
#pragma unroll
    for (int nj = 0; nj < 4; nj++) bias[nj] = b2g[wn + nj * 16 + fr];
    char* Cgb = (char*)(Out + ((size_t)bs * SEQ + (size_t)mt * 256) * HID + (size_t)nt * 256);

#pragma unroll
    for (int half = 0; half < 2; ++half) {
        if ((wn >> 7) == half) {
#pragma unroll
            for (int mi = 0; mi < 8; mi++)
#pragma unroll
                for (int nj = 0; nj < 4; nj++) {
                    const int lcol = (wn & 127) + nj * 16 + fr;
#pragma unroll
                    for (int r2 = 0; r2 < 4; r2++) {
                        const int row = wm + mi * 16 + fq * 4 + r2;
                        int byte = row * 512 + ((lcol * 4) ^ ((row & 7) << 4));
                        *(float*)(smem + byte) = acc[mi][nj][r2] + bias[nj];
                    }
                }
        }
        __syncthreads();
#pragma unroll
        for (int it = 0; it < 16; it++) {
            int chunk = tid + it * 512;
            int row = chunk >> 5;
            int cb  = (chunk & 31) * 16;
            f32x4 v = *(const f32x4*)(smem + row * 512 + (cb ^ ((row & 7) << 4)));
            __builtin_nontemporal_store(v, (f32x4*)(Cgb + (size_t)row * (HID * 4) + half * 512 + cb));
        }
        if (half == 0) __syncthreads();
    }
}

extern "C" void kernel_launch(void* const* d_in, const int* in_sizes, int n_in,
                              void* d_out, int out_size, void* d_ws, size_t ws_size,
                              hipStream_t stream) {
    const float* X      = (const float*)d_in[0];
    const int*   labels = (const int*)  d_in[1];
    const float* W1     = (const float*)d_in[2];
    const float* B1     = (const float*)d_in[3];
    const float* W2     = (const float*)d_in[4];
    const float* B2     = (const float*)d_in[5];
    float* Out = (float*)d_out;

    char* ws = (char*)d_ws;
    unsigned short* XbP = (unsigned short*)(ws);
    unsigned short* W1P = (unsigned short*)(ws + 25165824);
    unsigned short* W2P = (unsigned short*)(ws + 62914560);
    unsigned short* GP  = (unsigned short*)(ws + 100663296);
    int*            perm = (int*)(ws + 201326592);
    int*            cnt1 = (int*)(ws + 201326720);
    int*            cnt2 = (int*)(ws + 201326752);

    (void)hipFuncSetAttribute((const void*)moe_gemm1,
        hipFuncAttributeMaxDynamicSharedMemorySize, 131072);
    (void)hipFuncSetAttribute((const void*)moe_gemm2,
        hipFuncAttributeMaxDynamicSharedMemorySize, 131072);

    (void)hipMemsetAsync(cnt1, 0, 64, stream);

    prep_all<<<1 + 768 + 4608 + 4608, 256, 0, stream>>>(
        X, W1, W2, labels, XbP, W1P, W2P, perm);

    moe_gemm1<<<768, dim3(512), 131072, stream>>>(XbP, labels, perm, W1P, B1, GP, cnt1);
    moe_gemm2<<<192, dim3(512), 131072, stream>>>(GP, labels, perm, W2P, B2, Out, cnt2);
}

// Round 18
// 226.592 us; speedup vs baseline: 1.1487x; 1.1487x over previous
//
#include <hip/hip_runtime.h>
#include <hip/hip_bf16.h>

#define NB   32
#define SEQ  512
#define HID  768
#define FFN  3072
#define NEXP 8

typedef float f32x4 __attribute__((ext_vector_type(4)));
typedef short s16x8 __attribute__((ext_vector_type(8)));

__device__ __forceinline__ unsigned short f2bf(float f) {
    return __builtin_bit_cast(unsigned short, (__bf16)f);
}

__device__ __forceinline__ float fast_exp2(float x) {
    float r; asm("v_exp_f32 %0, %1" : "=v"(r) : "v"(x)); return r;
}
__device__ __forceinline__ float fast_rcp(float x) {
    float r; asm("v_rcp_f32 %0, %1" : "=v"(r) : "v"(x)); return r;
}

// tanh-gelu, overflow-free (exp2 arg <= 0). |error| vs exact-erf gelu ~2e-4.
__device__ __forceinline__ float gelu_fast(float v) {
    float u  = v * (0.7978845608f + 0.0356774081f * v * v);
    float t  = fast_exp2(-2.8853900817779268f * fabsf(u));
    float T  = (1.0f - t) * fast_rcp(1.0f + t);
    return 0.5f * v + 0.5f * fabsf(v) * T;
}

#define GLOAD16(gp, lp) __builtin_amdgcn_global_load_lds( \
    (const __attribute__((address_space(1))) unsigned int*)(gp), \
    (__attribute__((address_space(3))) unsigned int*)(lp), 16, 0, 0)

#define VMCNT(N) asm volatile("s_waitcnt vmcnt(%0)" :: "i"(N) : "memory")

// ---------------------------------------------------------------------------
// Merged prep (single launch): block 0 = label sort; 1..2048 = X fp32->bf16;
// 2049..6656 = W1 transpose; 6657..11264 = W2 transpose. All plain layouts.
// ---------------------------------------------------------------------------
__device__ __forceinline__ void transpose_body(
    const float* __restrict__ W, unsigned short* __restrict__ WT,
    unsigned short (*tile)[65], int R, int C, int bx, int by, int e, int tid)
{
    const int cb = bx * 64, rb = by * 64;
    const float* src = W + (size_t)e * R * C;
    unsigned short* dst = WT + (size_t)e * R * C;
    const int x = tid & 63, y0 = tid >> 6;
#pragma unroll
    for (int i = 0; i < 16; i++) {
        int r = y0 + i * 4;
        tile[r][x] = f2bf(src[(size_t)(rb + r) * C + cb + x]);
    }
    __syncthreads();
#pragma unroll
    for (int i = 0; i < 16; i++) {
        int c = y0 + i * 4;
        dst[(size_t)(cb + c) * R + rb + x] = tile[x][c];
    }
}

__global__ __launch_bounds__(256) void prep_all(
    const float* __restrict__ X, const float* __restrict__ W1,
    const float* __restrict__ W2, const int* __restrict__ labels,
    unsigned short* __restrict__ Xb, unsigned short* __restrict__ W1T,
    unsigned short* __restrict__ W2T, int* __restrict__ perm)
{
    __shared__ unsigned short tile[64][65];
    const int bid = blockIdx.x;
    const int tid = threadIdx.x;
    if (bid == 0) {
        if (tid < NB) {
            int li = labels[tid];
            int rank = 0;
            for (int j = 0; j < NB; j++) {
                int lj = labels[j];
                if (lj < li || (lj == li && j < tid)) rank++;
            }
            perm[rank] = tid;
        }
        return;
    }
    if (bid <= 2048) {
        const int n8 = NB * SEQ * HID / 8;
        int idx = (bid - 1) * 256 + tid;
        for (int i = idx; i < n8; i += 2048 * 256) {
            f32x4 a = *(const f32x4*)(X + (size_t)i * 8);
            f32x4 b = *(const f32x4*)(X + (size_t)i * 8 + 4);
            unsigned short o[8];
#pragma unroll
            for (int v = 0; v < 4; v++) o[v] = f2bf(a[v]);
#pragma unroll
            for (int v = 0; v < 4; v++) o[4 + v] = f2bf(b[v]);
            *(s16x8*)(Xb + (size_t)i * 8) = *(s16x8*)o;
        }
        return;
    }
    if (bid <= 2048 + 4608) {     // W1 [E][HID][FFN] -> W1T [E][FFN][HID]
        int idx = bid - 2049;
        transpose_body(W1, W1T, tile, HID, FFN, idx % 48, (idx / 48) % 12, idx / 576, tid);
        return;
    }
    {                             // W2 [E][FFN][HID] -> W2T [E][HID][FFN]
        int idx = bid - (2049 + 4608);
        transpose_body(W2, W2T, tile, FFN, HID, idx % 12, (idx / 12) % 48, idx / 576, tid);
    }
}

// ---------------------------------------------------------------------------
// 256x256 8-phase GEMM window machinery (BK=64, 8 waves, 2 x 64KB LDS bufs)
// ---------------------------------------------------------------------------
template<int LDB, bool ISA>
__device__ __forceinline__ void stage_region(const char* g, char* lds, int half, int tid)
{
#pragma unroll
    for (int p = 0; p < 2; p++) {
        int L  = p * 8192 + tid * 16;
        int rr = L >> 7;
        int cb = L & 127;
        int row = ISA ? ((rr & 63) + ((rr >> 6) << 7) + half * 64)
                      : ((rr & 31) + ((rr >> 5) << 6) + half * 32);
        int cbs = cb ^ ((row & 7) << 4);
        GLOAD16(g + (size_t)row * LDB + cbs, lds + (size_t)row * 128 + cb);
    }
}

__device__ __forceinline__ void read_af(const char* Ab, int arow_b, int k0, int ih, s16x8 (&a)[2][4])
{
    const int k1 = k0 ^ 64;
#pragma unroll
    for (int i = 0; i < 4; i++) {
        const char* p = Ab + arow_b + (ih * 64 + i * 16) * 128;
        a[0][i] = *(const s16x8*)(p + k0);
        a[1][i] = *(const s16x8*)(p + k1);
    }
}
__device__ __forceinline__ void read_bf(const char* Bb, int brow_b, int k0, int jh, s16x8 (&b)[2][2])
{
    const int k1 = k0 ^ 64;
#pragma unroll
    for (int j = 0; j < 2; j++) {
        const char* p = Bb + brow_b + (jh * 32 + j * 16) * 128;
        b[0][j] = *(const s16x8*)(p + k0);
        b[1][j] = *(const s16x8*)(p + k1);
    }
}

template<int IH, int JH>
__device__ __forceinline__ void mfma_quad(s16x8 (&a)[2][4], s16x8 (&b)[2][2], f32x4 (&acc)[8][4])
{
    __builtin_amdgcn_s_setprio(1);
#pragma unroll
    for (int kk = 0; kk < 2; kk++)
#pragma unroll
        for (int i = 0; i < 4; i++)
#pragma unroll
            for (int j = 0; j < 2; j++)
                acc[IH * 4 + i][JH * 2 + j] = __builtin_amdgcn_mfma_f32_16x16x32_bf16(
                    a[kk][i], b[kk][j], acc[IH * 4 + i][JH * 2 + j], 0, 0, 0);
    __builtin_amdgcn_s_setprio(0);
}

template<int LDB, bool S1, bool S2, int VM>
__device__ __forceinline__ void gwindow(const char* AgK, const char* BgK,
    char* Acur, char* Bcur, char* Anxt, char* Bnxt,
    int arow_b, int brow_b, int k0, int tid, f32x4 (&acc)[8][4])
{
    s16x8 a[2][4], b0[2][2], b1[2][2];
    read_af(Acur, arow_b, k0, 0, a);
    read_bf(Bcur, brow_b, k0, 0, b0);
    if constexpr (S1) stage_region<LDB, true >(AgK + 128, Anxt, 1, tid);
    __builtin_amdgcn_s_barrier();
    mfma_quad<0, 0>(a, b0, acc);
    __builtin_amdgcn_s_barrier();
    read_bf(Bcur, brow_b, k0, 1, b1);
    if constexpr (S1) stage_region<LDB, false>(BgK + 128, Bnxt, 1, tid);
    __builtin_amdgcn_s_barrier();
    mfma_quad<0, 1>(a, b1, acc);
    __builtin_amdgcn_s_barrier();
    read_af(Acur, arow_b, k0, 1, a);
    if constexpr (S2) stage_region<LDB, true >(AgK + 256, Acur, 0, tid);
    __builtin_amdgcn_s_barrier();
    mfma_quad<1, 1>(a, b1, acc);
    __builtin_amdgcn_s_barrier();
    if constexpr (S2) stage_region<LDB, false>(BgK + 256, Bcur, 0, tid);
    __builtin_amdgcn_s_barrier();
    mfma_quad<1, 0>(a, b0, acc);
    if constexpr (VM >= 0) VMCNT(VM);
    __builtin_amdgcn_s_barrier();
}

template<int LDB>
__device__ __forceinline__ void gemm_mainloop(const char* Ag, const char* Bg,
    char* smem, int KT, int tid, int arow_b, int brow_b, int k0, f32x4 (&acc)[8][4])
{
    stage_region<LDB, true >(Ag,       smem,          0, tid);
    stage_region<LDB, false>(Bg,       smem + 65536,  0, tid);
    stage_region<LDB, true >(Ag,       smem,          1, tid);
    stage_region<LDB, false>(Bg,       smem + 65536,  1, tid);
    stage_region<LDB, true >(Ag + 128, smem + 32768,  0, tid);
    stage_region<LDB, false>(Bg + 128, smem + 98304,  0, tid);
    VMCNT(4);
    __builtin_amdgcn_s_barrier();

    int cur = 0;
    for (int kt = 0; kt < KT - 2; ++kt) {
        char* Acur = smem + (cur << 15);
        char* Anxt = smem + ((cur ^ 1) << 15);
        char* Bcur = smem + 65536 + (cur << 15);
        char* Bnxt = smem + 65536 + ((cur ^ 1) << 15);
        gwindow<LDB, true, true, 4>(Ag + (size_t)kt * 128, Bg + (size_t)kt * 128,
            Acur, Bcur, Anxt, Bnxt, arow_b, brow_b, k0, tid, acc);
        cur ^= 1;
    }
    {
        char* Acur = smem + (cur << 15);
        char* Anxt = smem + ((cur ^ 1) << 15);
        char* Bcur = smem + 65536 + (cur << 15);
        char* Bnxt = smem + 65536 + ((cur ^ 1) << 15);
        gwindow<LDB, true, false, 0>(Ag + (size_t)(KT - 2) * 128, Bg + (size_t)(KT - 2) * 128,
            Acur, Bcur, Anxt, Bnxt, arow_b, brow_b, k0, tid, acc);
        cur ^= 1;
    }
    {
        char* Acur = smem + (cur << 15);
        char* Anxt = smem + ((cur ^ 1) << 15);
        char* Bcur = smem + 65536 + (cur << 15);
        char* Bnxt = smem + 65536 + ((cur ^ 1) << 15);
        gwindow<LDB, false, false, -1>(Ag + (size_t)(KT - 1) * 128, Bg + (size_t)(KT - 1) * 128,
            Acur, Bcur, Anxt, Bnxt, arow_b, brow_b, k0, tid, acc);
    }
}

// ---------------------------------------------------------------------------
// Kernel 1: G = gelu(Xb @ W1[e] + b1[e]) -> bf16 (R10 best-measured variant)
// ---------------------------------------------------------------------------
__global__ __launch_bounds__(512, 2) void moe_gemm1(
    const unsigned short* __restrict__ Xb,
    const int*   __restrict__ labels,
    const int*   __restrict__ perm,
    const unsigned short* __restrict__ W1T,  // [E][FFN][HID]
    const float* __restrict__ B1,
    unsigned short* __restrict__ G)
{
    extern __shared__ char smem[];
    const int L = blockIdx.x;
    const int xcd  = L & 7;
    const int r    = L >> 8;          // band 0..2
    const int i    = (L >> 3) & 31;
    const int pair = i >> 2;          // 0..7
    const int bs = perm[xcd * 4 + (pair >> 1)];
    const int mt = pair & 1;
    const int nt = r * 4 + (i & 3);
    const int e  = labels[bs];

    const char* Ag = (const char*)(Xb + ((size_t)bs * SEQ + (size_t)mt * 256) * HID);
    const char* Bg = (const char*)(W1T + (size_t)e * FFN * HID + (size_t)nt * 256 * HID);

    const int tid = threadIdx.x;
    const int lane = tid & 63, w = tid >> 6;
    const int wm = (w >> 2) * 128, wn = (w & 3) * 64;
    const int fr = lane & 15, fq = lane >> 4;
    const int arow_b = (wm + fr) * 128, brow_b = (wn + fr) * 128;
    const int k0 = (fq * 16) ^ ((fr & 7) << 4);

    f32x4 acc[8][4];
#pragma unroll
    for (int i2 = 0; i2 < 8; i2++)
#pragma unroll
        for (int j = 0; j < 4; j++) acc[i2][j] = (f32x4)0.0f;

    gemm_mainloop<HID * 2>(Ag, Bg, smem, HID / 64, tid, arow_b, brow_b, k0, acc);

    // ---- epilogue: bias+gelu -> LDS bf16 tile [256][256] (XOR-swizzled) ----
    const float* b1g = B1 + (size_t)e * FFN + (size_t)nt * 256;
    float bias[4];
#pragma unroll
    for (int nj = 0; nj < 4; nj++) bias[nj] = b1g[wn + nj * 16 + fr];
#pragma unroll
    for (int mi = 0; mi < 8; mi++)
#pragma unroll
        for (int nj = 0; nj < 4; nj++) {
            const int col = wn + nj * 16 + fr;
#pragma unroll
            for (int r2 = 0; r2 < 4; r2++) {
                const int row = wm + mi * 16 + fq * 4 + r2;
                float v = acc[mi][nj][r2] + bias[nj];
                int byte = row * 512 + ((col * 2) ^ ((row & 7) << 4));
                *(unsigned short*)(smem + byte) = f2bf(gelu_fast(v));
            }
        }
    __syncthreads();
    // ---- stream out: 16B/lane fully-coalesced nontemporal (full lines) ----
    char* Cgb = (char*)(G + ((size_t)bs * SEQ + (size_t)mt * 256) * FFN + (size_t)nt * 256);
#pragma unroll
    for (int it = 0; it < 16; it++) {
        int chunk = tid + it * 512;       // 0..8191
        int row = chunk >> 5;
        int cb  = (chunk & 31) * 16;
        s16x8 v = *(const s16x8*)(smem + row * 512 + (cb ^ ((row & 7) << 4)));
        __builtin_nontemporal_store(v, (s16x8*)(Cgb + (size_t)row * (FFN * 2) + cb));
    }
}

// ---------------------------------------------------------------------------
// Kernel 2: Out = G @ W2[e] + b2[e] -> fp32; LDS-coalesced NT epilogue.
// ---------------------------------------------------------------------------
__global__ __launch_bounds__(512, 2) void moe_gemm2(
    const unsigned short* __restrict__ G,
    const int*   __restrict__ labels,
    const int*   __restrict__ perm,
    const unsigned short* __restrict__ W2T,  // [E][HID][FFN]
    const float* __restrict__ B2,
    float* __restrict__ Out)
{
    extern __shared__ char smem[];
    const int L = blockIdx.x;
    const int xcd = L & 7, s = L >> 3;       // s in [0,24)
    const int bs = perm[xcd * 4 + s / 6];
    const int rr = s % 6;
    const int mt = rr / 3, nt = rr % 3;
    const int e  = labels[bs];

    const char* Ag = (const char*)(G + ((size_t)bs * SEQ + (size_t)mt * 256) * FFN);
    const char* Bg = (const char*)(W2T + (size_t)e * HID * FFN + (size_t)nt * 256 * FFN);

    const int tid = threadIdx.x;
    const int lane = tid & 63, w = tid >> 6;
    const int wm = (w >> 2) * 128, wn = (w & 3) * 64;
    const int fr = lane & 15, fq = lane >> 4;
    const int arow_b = (wm + fr) * 128, brow_b = (wn + fr) * 128;
    const int k0 = (fq * 16) ^ ((fr & 7) << 4);

    f32x4 acc[8][4];
#pragma unroll
    for (int i = 0; i < 8; i++)
#pragma unroll
        for (int j = 0; j < 4; j++) acc[i][j] = (f32x4)0.0f;

    gemm_mainloop<FFN * 2>(Ag, Bg, smem, FFN / 64, tid, arow_b, brow_b, k0, acc);

    const float* b2g = B2 + (size_t)e * HID + (size_t)nt * 256;
    float bias[4];
#pragma unroll
    for (int nj = 0; nj < 4; nj++) bias[nj] = b2g[wn + nj * 16 + fr];
    char* Cgb = (char*)(Out + ((size_t)bs * SEQ + (size_t)mt * 256) * HID + (size_t)nt * 256);

#pragma unroll
    for (int half = 0; half < 2; ++half) {
        if ((wn >> 7) == half) {
#pragma unroll
            for (int mi = 0; mi < 8; mi++)
#pragma unroll
                for (int nj = 0; nj < 4; nj++) {
                    const int lcol = (wn & 127) + nj * 16 + fr;   // 0..127
#pragma unroll
                    for (int r2 = 0; r2 < 4; r2++) {
                        const int row = wm + mi * 16 + fq * 4 + r2;
                        int byte = row * 512 + ((lcol * 4) ^ ((row & 7) << 4));
                        *(float*)(smem + byte) = acc[mi][nj][r2] + bias[nj];
                    }
                }
        }
        __syncthreads();
#pragma unroll
        for (int it = 0; it < 16; it++) {
            int chunk = tid + it * 512;
            int row = chunk >> 5;
            int cb  = (chunk & 31) * 16;
            f32x4 v = *(const f32x4*)(smem + row * 512 + (cb ^ ((row & 7) << 4)));
            __builtin_nontemporal_store(v, (f32x4*)(Cgb + (size_t)row * (HID * 4) + half * 512 + cb));
        }
        if (half == 0) __syncthreads();
    }
}

extern "C" void kernel_launch(void* const* d_in, const int* in_sizes, int n_in,
                              void* d_out, int out_size, void* d_ws, size_t ws_size,
                              hipStream_t stream) {
    const float* X      = (const float*)d_in[0];
    const int*   labels = (const int*)  d_in[1];
    const float* W1     = (const float*)d_in[2];
    const float* B1     = (const float*)d_in[3];
    const float* W2     = (const float*)d_in[4];
    const float* B2     = (const float*)d_in[5];
    float* Out = (float*)d_out;

    char* ws = (char*)d_ws;
    unsigned short* Xb  = (unsigned short*)(ws);               // 25,165,824 B
    unsigned short* W1T = (unsigned short*)(ws + 25165824);    // 37,748,736 B
    unsigned short* W2T = (unsigned short*)(ws + 62914560);    // 37,748,736 B
    unsigned short* G   = (unsigned short*)(ws + 100663296);   // 100,663,296 B
    int*            perm = (int*)(ws + 201326592);             // 128 B

    (void)hipFuncSetAttribute((const void*)moe_gemm1,
        hipFuncAttributeMaxDynamicSharedMemorySize, 131072);
    (void)hipFuncSetAttribute((const void*)moe_gemm2,
        hipFuncAttributeMaxDynamicSharedMemorySize, 131072);

    // single merged prep: sort(1) + cvt_x(2048) + W1T(4608) + W2T(4608)
    prep_all<<<1 + 2048 + 4608 + 4608, 256, 0, stream>>>(
        X, W1, W2, labels, Xb, W1T, W2T, perm);

    moe_gemm1<<<768, dim3(512), 131072, stream>>>(Xb, labels, perm, W1T, B1, G);
    moe_gemm2<<<192, dim3(512), 131072, stream>>>(G, labels, perm, W2T, B2, Out);
}